// Round 8
// baseline (495.321 us; speedup 1.0000x reference)
//
#include <hip/hip_runtime.h>

// Problem constants (match reference)
#define C 80
#define P 30000
#define G 800
#define BS 256
#define NB 8          // spatial bins per dimension (cell = 128 px, box extent <= 128)
#define NC (NB * NB)  // 64 cells per class
#define P_BLK ((P + BS - 1) / BS)    // 118

// rank order = score desc, then pred-index asc. Packed key is monotone in that
// order (scores >= 0 so float bits are order-preserving). key==0 means "no
// match" (needs score==0.0f AND p==P-1 — probability ~0).
__device__ __forceinline__ unsigned long long pack_key(float s, int p) {
    return ((unsigned long long)__float_as_uint(s) << 32) | (unsigned)(P - 1 - p);
}

// cell of a box by its (x1,y1); boxes span <= 2 cells/dim, so all overlap
// partners of a cell-(bx,by) box lie in the 3x3 cell neighborhood.
__device__ __forceinline__ int cell_of(float x1, float y1) {
    int bx = (int)(x1 * (1.0f / 128.0f));
    int by = (int)(y1 * (1.0f / 128.0f));
    bx = min(max(bx, 0), NB - 1);
    by = min(max(by, 0), NB - 1);
    return by * NB + bx;
}

// ---------------- L1: pred prep (x < P_BLK) + gt binning (x == P_BLK) -------
// pred blocks: LDS cell hist -> one no-return global atomic per (block,cell);
// extract score column. gt block (one per class): count+scan+scatter the 800
// GTs into cell-packed lists; zero this class's gtKey slice.
__global__ __launch_bounds__(BS) void prep_kernel(
        const float* __restrict__ pred, const float* __restrict__ gt,
        int* __restrict__ predCnt, float* __restrict__ scoreC,
        int* __restrict__ gtCnt, int* __restrict__ gtOff,
        float4* __restrict__ gtBox, float* __restrict__ gtAbe,
        int* __restrict__ gtIdx, unsigned long long* __restrict__ gtKey) {
    __shared__ int h[NC], cur[NC];
    __shared__ int gcell[G];
    const int c = blockIdx.y, tid = threadIdx.x;
    if (blockIdx.x < P_BLK) {
        // ---- pred prep ----
        if (tid < NC) h[tid] = 0;
        __syncthreads();
        int p = blockIdx.x * BS + tid;
        if (p < P) {
            const float* r = pred + ((size_t)c * P + p) * 7;
            scoreC[(size_t)c * P + p] = r[2];
            atomicAdd(&h[cell_of(r[3], r[4])], 1);   // LDS
        }
        __syncthreads();
        if (tid < NC && h[tid]) atomicAdd(&predCnt[c * NC + tid], h[tid]);   // no-return
        return;
    }
    // ---- gt binning (block x == P_BLK) ----
    if (tid < NC) h[tid] = 0;
    for (int i = tid; i < G; i += BS) gtKey[c * G + i] = 0ull;
    __syncthreads();
    for (int i = tid; i < G; i += BS) {
        const float* r = gt + ((size_t)c * G + i) * 7;
        int cl = cell_of(r[3], r[4]);
        gcell[i] = cl;
        atomicAdd(&h[cl], 1);
    }
    __syncthreads();
    if (tid < 64) {   // wave 0: exclusive scan over 64 cells
        int v = h[tid], s = v;
        for (int o = 1; o < 64; o <<= 1) { int t = __shfl_up(s, o); if (tid >= o) s += t; }
        int excl = s - v;
        cur[tid] = excl;
        gtOff[c * NC + tid] = excl;
        gtCnt[c * NC + tid] = v;
    }
    __syncthreads();
    for (int i = tid; i < G; i += BS) {
        const float* r = gt + ((size_t)c * G + i) * 7;   // L1-hot (2nd pass)
        float x1 = r[3], y1 = r[4], x2 = r[5], y2 = r[6];
        int slot = atomicAdd(&cur[gcell[i]], 1);
        gtBox[c * G + slot] = make_float4(x1, y1, x2, y2);
        // area + eps pre-folded: cross-compare uses sb = A + (area_g + eps);
        // the -inter terms of the two denominators cancel algebraically.
        gtAbe[c * G + slot] = __fadd_rn(__fmul_rn(__fsub_rn(x2, x1), __fsub_rn(y2, y1)), 1e-9f);
        gtIdx[c * G + slot] = i;
    }
}

// ---------------- L2: scatter preds into cell-sorted box staging ------------
// In-block wave scan of predCnt replaces the old pred_scan kernel; slot =
// inblock-scan offset + global cursor (predCur0 zero-initialized by memset) +
// LDS local rank. Writes box + pid in cell order so match reads coalesced.
__global__ __launch_bounds__(BS) void scatter_kernel(
        const float* __restrict__ pred, const int* __restrict__ predCnt,
        int* __restrict__ predCur0,
        float4* __restrict__ sBox, unsigned short* __restrict__ sPid) {
    __shared__ int h[NC], base[NC], sOff[NC];
    const int c = blockIdx.y, tid = threadIdx.x;
    if (tid < NC) h[tid] = 0;
    if (tid < 64) {   // wave 0: exclusive scan of this class's cell counts
        int v = predCnt[c * NC + tid], s = v;
        for (int o = 1; o < 64; o <<= 1) { int t = __shfl_up(s, o); if (tid >= o) s += t; }
        sOff[tid] = s - v;
    }
    __syncthreads();
    int p = blockIdx.x * BS + tid;
    float4 box = make_float4(0.f, 0.f, 0.f, 0.f);
    int cellv = 0, lr = 0;
    if (p < P) {
        const float* r = pred + ((size_t)c * P + p) * 7;
        box = make_float4(r[3], r[4], r[5], r[6]);
        cellv = cell_of(box.x, box.y);
        lr = atomicAdd(&h[cellv], 1);   // LDS local rank
    }
    __syncthreads();
    if (tid < NC && h[tid])
        base[tid] = sOff[tid] + atomicAdd(&predCur0[c * NC + tid], h[tid]);
    __syncthreads();
    if (p < P) {
        int slot = base[cellv] + lr;
        sBox[(size_t)c * P + slot] = box;
        sPid[(size_t)c * P + slot] = (unsigned short)p;
    }
}

// ---------------- L3: match, one block per (cell, class), 2 preds/thread ----
// 3x3 GT neighborhood staged ONCE per (cell,class). Each j-iteration serves
// two preds off one sB/sE read — two independent (IN,SB,mj) cndmask chains
// fill the dependency-latency bubbles that capped R7 at 237 us (loads are now
// coalesced float4 staging, unlike R6's scattered rows). Argmax via cancelled
// cross-multiply (iou_g > iou_best <=> in_g*sb_b > in_b*sb_g, sb = A +
// area_g + eps). Epilogue recomputes the reference-order denominator exactly,
// so the >0.5 test uses the bit-exact reference iou.
__global__ __launch_bounds__(BS) void match_kernel(
        const int* __restrict__ predCnt,
        const int* __restrict__ gtOff, const int* __restrict__ gtCnt,
        const float4* __restrict__ gtBox, const float* __restrict__ gtAbe,
        const int* __restrict__ gtIdx,
        const float4* __restrict__ sBox, const unsigned short* __restrict__ sPid,
        const float* __restrict__ scoreC,
        unsigned long long* __restrict__ gtKey) {
    __shared__ float4 sB[G];
    __shared__ float  sE[G];
    __shared__ int    sG[G];
    __shared__ int    sOff[NC], sCnt[NC];
    const int c = blockIdx.y, cell = blockIdx.x;
    const int tid = threadIdx.x;

    if (tid < 64) {   // wave 0: exclusive scan of this class's cell counts
        int v = predCnt[c * NC + tid], s = v;
        for (int o = 1; o < 64; o <<= 1) { int t = __shfl_up(s, o); if (tid >= o) s += t; }
        sOff[tid] = s - v; sCnt[tid] = v;
    }
    __syncthreads();
    const int pOff = sOff[cell], pCnt = sCnt[cell];
    if (pCnt == 0) return;   // block-uniform (border cells)

    const int cx = cell & (NB - 1), cy = cell >> 3;
    int total = 0;
    for (int dy = -1; dy <= 1; ++dy) {
        int yy = cy + dy; if (yy < 0 || yy >= NB) continue;
        for (int dx = -1; dx <= 1; ++dx) {
            int xx = cx + dx; if (xx < 0 || xx >= NB) continue;
            int nc = yy * NB + xx;
            int off = gtOff[c * NC + nc], cnt = gtCnt[c * NC + nc];
            for (int i = tid; i < cnt; i += BS) {
                sB[total + i] = gtBox[c * G + off + i];
                sE[total + i] = gtAbe[c * G + off + i];
                sG[total + i] = gtIdx[c * G + off + i];
            }
            total += cnt;   // uniform across threads
        }
    }
    __syncthreads();

    const size_t cp = (size_t)c * P;
    for (int i0 = tid; i0 < pCnt; i0 += 2 * BS) {
        const int  i1 = i0 + BS;
        const bool a1 = (i1 < pCnt);
        float4 pb0 = sBox[cp + pOff + i0];                    // coalesced
        float4 pb1 = sBox[cp + pOff + (a1 ? i1 : i0)];        // coalesced
        float A0 = __fmul_rn(__fsub_rn(pb0.z, pb0.x), __fsub_rn(pb0.w, pb0.y));
        float A1 = __fmul_rn(__fsub_rn(pb1.z, pb1.x), __fsub_rn(pb1.w, pb1.y));
        float IN0 = 0.0f, SB0 = 1.0f; int m0 = -1;
        float IN1 = 0.0f, SB1 = 1.0f; int m1 = -1;
        #pragma unroll 2
        for (int j = 0; j < total; ++j) {
            float4 b = sB[j];
            float  e = sE[j];
            float lx = fmaxf(pb0.x, b.x), ly = fmaxf(pb0.y, b.y);
            float rx = fminf(pb0.z, b.z), ry = fminf(pb0.w, b.w);
            float wx = fmaxf(__fsub_rn(rx, lx), 0.0f);
            float wy = fmaxf(__fsub_rn(ry, ly), 0.0f);
            float in = __fmul_rn(wx, wy);
            float sb = __fadd_rn(A0, e);
            bool  up = __fmul_rn(in, SB0) > __fmul_rn(IN0, sb);
            IN0 = up ? in : IN0; SB0 = up ? sb : SB0; m0 = up ? j : m0;

            lx = fmaxf(pb1.x, b.x); ly = fmaxf(pb1.y, b.y);
            rx = fminf(pb1.z, b.z); ry = fminf(pb1.w, b.w);
            wx = fmaxf(__fsub_rn(rx, lx), 0.0f);
            wy = fmaxf(__fsub_rn(ry, ly), 0.0f);
            in = __fmul_rn(wx, wy);
            sb = __fadd_rn(A1, e);
            up = __fmul_rn(in, SB1) > __fmul_rn(IN1, sb);
            IN1 = up ? in : IN1; SB1 = up ? sb : SB1; m1 = up ? j : m1;
        }
        if (IN0 > 0.0f) {   // zero-inter preds can never be valid
            float4 b = sB[m0];
            float area = __fmul_rn(__fsub_rn(b.z, b.x), __fsub_rn(b.w, b.y));
            float dn = __fadd_rn(__fsub_rn(__fadd_rn(A0, area), IN0), 1e-9f);
            if (__fdiv_rn(IN0, dn) > 0.5f) {   // exact reference iou
                int p = (int)sPid[cp + pOff + i0];
                atomicMax(&gtKey[c * G + sG[m0]], pack_key(scoreC[cp + p], p));
            }
        }
        if (a1 && IN1 > 0.0f) {
            float4 b = sB[m1];
            float area = __fmul_rn(__fsub_rn(b.z, b.x), __fsub_rn(b.w, b.y));
            float dn = __fadd_rn(__fsub_rn(__fadd_rn(A1, area), IN1), 1e-9f);
            if (__fdiv_rn(IN1, dn) > 0.5f) {
                int p = (int)sPid[cp + pOff + i1];
                atomicMax(&gtKey[c * G + sG[m1]], pack_key(scoreC[cp + p], p));
            }
        }
    }
}

// ---------------- L4: finale — compact+sort+hist+prefix+AP+mean, 1 blk/class
// TP keys compacted from gtKey (LDS atomic), position-sorted (O(T^2) LDS
// broadcast, keys unique, T <= 800) into a 1024-padded descending array.
// Every pred binary-searches its pos = #{TP keys > key_q} -> LDS histogram;
// inclusive prefix gives rank r = prefix[s]-1 for the TP at sorted position
// s (ordinal k = s+1). precision = k/(r+1) exactly (ctp+cfp == r+1; the 1e-9
// rounds away in f32); term = ((k/800-(k-1)/800)*(k/(r+1)+(k-1)/r))*0.5 —
// reference op order; r==0 contributes nothing. Last-arriving class block
// computes the mean with a deterministic serial in-order sum.
__global__ __launch_bounds__(BS) void finale_kernel(
        const unsigned long long* __restrict__ gtKey,
        const float* __restrict__ scoreC,
        float* __restrict__ ap, int* __restrict__ doneCnt,
        float* __restrict__ out) {
    __shared__ unsigned long long k[G];
    __shared__ unsigned long long sk[1024];
    __shared__ int ha[1024];
    __shared__ int hb[1024];
    __shared__ float red[BS];
    __shared__ float sap[C];
    __shared__ int cnt, lastFlag;
    const int c = blockIdx.x, tid = threadIdx.x;
    if (tid == 0) cnt = 0;
    for (int j = tid; j < 1024; j += BS) { sk[j] = 0ull; ha[j] = 0; }
    __syncthreads();
    for (int i = tid; i < G; i += BS) {
        unsigned long long key = gtKey[c * G + i];
        if (key != 0ull) k[atomicAdd(&cnt, 1)] = key;
    }
    __syncthreads();
    const int T = cnt;
    for (int t = tid; t < T; t += BS) {
        unsigned long long key = k[t];
        int pos = 0;
        for (int u = 0; u < T; ++u) pos += (k[u] > key) ? 1 : 0;   // keys unique
        sk[pos] = key;
    }
    __syncthreads();
    // histogram of pred positions via binary search into sk (desc, 0-padded)
    const float* sc = scoreC + (size_t)c * P;
    for (int i = tid; i < P; i += BS) {
        unsigned long long kq =
            ((unsigned long long)__float_as_uint(sc[i]) << 32) | (unsigned)(P - 1 - i);
        int lo = 0;   // count of keys > kq (pads are 0, never > kq)
        #pragma unroll
        for (int step = 512; step > 0; step >>= 1)
            if (sk[lo + step - 1] > kq) lo += step;
        atomicAdd(&ha[lo], 1);   // LDS
    }
    __syncthreads();
    int* src = ha; int* dst = hb;
    for (int o = 1; o < 1024; o <<= 1) {
        for (int j = tid; j < 1024; j += BS)
            dst[j] = src[j] + ((j >= o) ? src[j - o] : 0);
        __syncthreads();
        int* tmp = src; src = dst; dst = tmp;
    }
    float sum = 0.0f;
    for (int s = tid; s < T; s += BS) {
        int r = src[s] - 1;          // inclusive prefix minus self
        if (r >= 1) {
            float kf  = (float)(s + 1);
            float km  = (float)s;
            float ri  = __fdiv_rn(kf, 800.0f);
            float rim = __fdiv_rn(km, 800.0f);
            float pi  = __fdiv_rn(kf, (float)(r + 1));
            float pim = __fdiv_rn(km, (float)r);
            sum = __fadd_rn(sum,
                  __fmul_rn(__fmul_rn(__fsub_rn(ri, rim), __fadd_rn(pi, pim)), 0.5f));
        }
    }
    red[tid] = sum;
    __syncthreads();
    for (int s2 = BS / 2; s2 > 0; s2 >>= 1) {
        if (tid < s2) red[tid] = __fadd_rn(red[tid], red[tid + s2]);
        __syncthreads();
    }
    if (tid == 0) {
        ap[c] = red[0];
        __threadfence();                                  // publish ap[c]
        lastFlag = (atomicAdd(doneCnt, 1) == C - 1);      // device-scope
    }
    __syncthreads();
    if (lastFlag) {
        __threadfence();                                  // acquire all ap[]
        if (tid < C) sap[tid] = ((volatile float*)ap)[tid];
        __syncthreads();
        if (tid == 0) {
            float s = 0.0f;
            for (int cc = 0; cc < C; ++cc) s = __fadd_rn(s, sap[cc]);
            out[0] = __fdiv_rn(s, 80.0f);
        }
    }
}

extern "C" void kernel_launch(void* const* d_in, const int* in_sizes, int n_in,
                              void* d_out, int out_size, void* d_ws, size_t ws_size,
                              hipStream_t stream) {
    const float* pred = (const float*)d_in[0];   // [C, P, 7] f32
    const float* gt   = (const float*)d_in[1];   // [C, G, 7] f32
    float* out = (float*)d_out;

    // Workspace layout (~54.9 MB; fits the >=56 MB confirmed by R7 running the
    // staged path). [0, 41024) is the memset-zeroed region (doneCnt, predCnt,
    // predCur0); gtKey is zeroed by prep's gt blocks.
    char* ws = (char*)d_ws;
    int*                doneCnt  = (int*)               (ws + 0);         // 4 B
    int*                predCnt  = (int*)               (ws + 64);        // 20480 B
    int*                predCur0 = (int*)               (ws + 20544);     // 20480 B
    float*              ap       = (float*)             (ws + 41024);     // 320 B
    int*                gtCnt    = (int*)               (ws + 41472);     // 20480 B
    int*                gtOff    = (int*)               (ws + 61952);     // 20480 B
    int*                gtIdx    = (int*)               (ws + 82432);     // 256000 B
    float*              gtAbe    = (float*)             (ws + 338432);    // 256000 B
    unsigned long long* gtKey    = (unsigned long long*)(ws + 594432);    // 512000 B
    float4*             gtBox    = (float4*)            (ws + 1106432);   // 1.024 MB (16-aligned)
    float*              scoreC   = (float*)             (ws + 2130432);   // 9.6 MB
    float4*             sBox     = (float4*)            (ws + 11730432);  // 38.4 MB (16-aligned)
    unsigned short*     sPid     = (unsigned short*)    (ws + 50130432);  // 4.8 MB
    // end: 54930432 B

    hipMemsetAsync(ws, 0, 41024, stream);   // doneCnt + predCnt + predCur0
    prep_kernel<<<dim3(P_BLK + 1, C), BS, 0, stream>>>(
        pred, gt, predCnt, scoreC, gtCnt, gtOff, gtBox, gtAbe, gtIdx, gtKey);
    scatter_kernel<<<dim3(P_BLK, C), BS, 0, stream>>>(
        pred, predCnt, predCur0, sBox, sPid);
    match_kernel<<<dim3(NC, C), BS, 0, stream>>>(
        predCnt, gtOff, gtCnt, gtBox, gtAbe, gtIdx, sBox, sPid, scoreC, gtKey);
    finale_kernel<<<C, BS, 0, stream>>>(gtKey, scoreC, ap, doneCnt, out);
}

// Round 9
// 390.884 us; speedup vs baseline: 1.2672x; 1.2672x over previous
//
#include <hip/hip_runtime.h>

// Problem constants (match reference)
#define C 80
#define P 30000
#define G 800
#define BS 256
#define MBS 512       // match block size (4 blocks/CU by thread cap -> 32 waves/CU)
#define NB 8          // spatial bins per dimension (cell = 128 px, box extent <= 128)
#define NC (NB * NB)  // 64 cells per class
#define HCH 8         // hist chunks per class
#define CHSZ ((P + HCH - 1) / HCH)   // 3750
#define P_BLK ((P + BS - 1) / BS)    // 118

// rank order = score desc, then pred-index asc. Packed key is monotone in that
// order (scores >= 0 so float bits are order-preserving). key==0 means "no
// match" (needs score==0.0f AND p==P-1 — probability ~0).
__device__ __forceinline__ unsigned long long pack_key(float s, int p) {
    return ((unsigned long long)__float_as_uint(s) << 32) | (unsigned)(P - 1 - p);
}

// cell of a box by its (x1,y1); boxes span <= 2 cells/dim, so all overlap
// partners of a cell-(bx,by) box lie in the 3x3 cell neighborhood.
__device__ __forceinline__ int cell_of(float x1, float y1) {
    int bx = (int)(x1 * (1.0f / 128.0f));
    int by = (int)(y1 * (1.0f / 128.0f));
    bx = min(max(bx, 0), NB - 1);
    by = min(max(by, 0), NB - 1);
    return by * NB + bx;
}

// ---------------- L1: pred prep (x < P_BLK) + gt binning (x == P_BLK) -------
// pred blocks: LDS cell hist -> one no-return global atomic per (block,cell);
// extract score column. gt block (one per class): count+scan+scatter the 800
// GTs into cell-packed lists; zero this class's gtKey slice.
__global__ __launch_bounds__(BS) void prep_kernel(
        const float* __restrict__ pred, const float* __restrict__ gt,
        int* __restrict__ predCnt, float* __restrict__ scoreC,
        int* __restrict__ gtCnt, int* __restrict__ gtOff,
        float4* __restrict__ gtBox, float* __restrict__ gtAbe,
        int* __restrict__ gtIdx, unsigned long long* __restrict__ gtKey) {
    __shared__ int h[NC], cur[NC];
    __shared__ int gcell[G];
    const int c = blockIdx.y, tid = threadIdx.x;
    if (blockIdx.x < P_BLK) {
        // ---- pred prep ----
        if (tid < NC) h[tid] = 0;
        __syncthreads();
        int p = blockIdx.x * BS + tid;
        if (p < P) {
            const float* r = pred + ((size_t)c * P + p) * 7;
            scoreC[(size_t)c * P + p] = r[2];
            atomicAdd(&h[cell_of(r[3], r[4])], 1);   // LDS
        }
        __syncthreads();
        if (tid < NC && h[tid]) atomicAdd(&predCnt[c * NC + tid], h[tid]);   // no-return
        return;
    }
    // ---- gt binning (block x == P_BLK) ----
    if (tid < NC) h[tid] = 0;
    for (int i = tid; i < G; i += BS) gtKey[c * G + i] = 0ull;
    __syncthreads();
    for (int i = tid; i < G; i += BS) {
        const float* r = gt + ((size_t)c * G + i) * 7;
        int cl = cell_of(r[3], r[4]);
        gcell[i] = cl;
        atomicAdd(&h[cl], 1);
    }
    __syncthreads();
    if (tid < 64) {   // wave 0: exclusive scan over 64 cells
        int v = h[tid], s = v;
        for (int o = 1; o < 64; o <<= 1) { int t = __shfl_up(s, o); if (tid >= o) s += t; }
        int excl = s - v;
        cur[tid] = excl;
        gtOff[c * NC + tid] = excl;
        gtCnt[c * NC + tid] = v;
    }
    __syncthreads();
    for (int i = tid; i < G; i += BS) {
        const float* r = gt + ((size_t)c * G + i) * 7;   // L1-hot (2nd pass)
        float x1 = r[3], y1 = r[4], x2 = r[5], y2 = r[6];
        int slot = atomicAdd(&cur[gcell[i]], 1);
        gtBox[c * G + slot] = make_float4(x1, y1, x2, y2);
        // area + eps pre-folded: cross-compare uses sb = A + (area_g + eps);
        // the -inter terms of the two denominators cancel algebraically.
        gtAbe[c * G + slot] = __fadd_rn(__fmul_rn(__fsub_rn(x2, x1), __fsub_rn(y2, y1)), 1e-9f);
        gtIdx[c * G + slot] = i;
    }
}

// ---------------- L2: scatter preds into cell-sorted box staging ------------
// In-block wave scan of predCnt (no separate scan kernel); slot = scan offset
// + global cursor (predCur0 memset-zeroed) + LDS local rank. Writes box + pid
// in cell order so match reads coalesced float4.
__global__ __launch_bounds__(BS) void scatter_kernel(
        const float* __restrict__ pred, const int* __restrict__ predCnt,
        int* __restrict__ predCur0,
        float4* __restrict__ sBox, unsigned short* __restrict__ sPid) {
    __shared__ int h[NC], base[NC], sOff[NC];
    const int c = blockIdx.y, tid = threadIdx.x;
    if (tid < NC) h[tid] = 0;
    if (tid < 64) {   // wave 0: exclusive scan of this class's cell counts
        int v = predCnt[c * NC + tid], s = v;
        for (int o = 1; o < 64; o <<= 1) { int t = __shfl_up(s, o); if (tid >= o) s += t; }
        sOff[tid] = s - v;
    }
    __syncthreads();
    int p = blockIdx.x * BS + tid;
    float4 box = make_float4(0.f, 0.f, 0.f, 0.f);
    int cellv = 0, lr = 0;
    if (p < P) {
        const float* r = pred + ((size_t)c * P + p) * 7;
        box = make_float4(r[3], r[4], r[5], r[6]);
        cellv = cell_of(box.x, box.y);
        lr = atomicAdd(&h[cellv], 1);   // LDS local rank
    }
    __syncthreads();
    if (tid < NC && h[tid])
        base[tid] = sOff[tid] + atomicAdd(&predCur0[c * NC + tid], h[tid]);
    __syncthreads();
    if (p < P) {
        int slot = base[cellv] + lr;
        sBox[(size_t)c * P + slot] = box;
        sPid[(size_t)c * P + slot] = (unsigned short)p;
    }
}

// ---------------- L3: match, one 512-thread block per (cell, class) ---------
// Proven R7 inner body (1 pred/thread, unroll 4) in 512-thread blocks:
// 4 blocks/CU (thread cap) x 8 waves = 32 waves/CU theoretical residency vs
// the ~12.5 measured at 256 threads — attacks the latency-hiding deficit
// (real issue util ~36%; dependency chain + LDS latency dominated). GT
// neighborhood staged ONCE per (cell,class) — 3x fewer stagings than R7.
// Argmax via cancelled cross-multiply (iou_g > iou_best <=> in_g*sb_b >
// in_b*sb_g, sb = A + area_g + eps). Epilogue recomputes the reference-order
// denominator exactly, so the >0.5 test uses the bit-exact reference iou.
__global__ __launch_bounds__(MBS) void match_kernel(
        const int* __restrict__ predCnt,
        const int* __restrict__ gtOff, const int* __restrict__ gtCnt,
        const float4* __restrict__ gtBox, const float* __restrict__ gtAbe,
        const int* __restrict__ gtIdx,
        const float4* __restrict__ sBox, const unsigned short* __restrict__ sPid,
        const float* __restrict__ scoreC,
        unsigned long long* __restrict__ gtKey) {
    __shared__ float4 sB[G];
    __shared__ float  sE[G];
    __shared__ int    sG[G];
    __shared__ int    sOff[NC], sCnt[NC];
    const int c = blockIdx.y, cell = blockIdx.x;
    const int tid = threadIdx.x;

    if (tid < 64) {   // wave 0: exclusive scan of this class's cell counts
        int v = predCnt[c * NC + tid], s = v;
        for (int o = 1; o < 64; o <<= 1) { int t = __shfl_up(s, o); if (tid >= o) s += t; }
        sOff[tid] = s - v; sCnt[tid] = v;
    }
    __syncthreads();
    const int pOff = sOff[cell], pCnt = sCnt[cell];
    if (pCnt == 0) return;   // block-uniform (empty cells)

    const int cx = cell & (NB - 1), cy = cell >> 3;
    int total = 0;
    for (int dy = -1; dy <= 1; ++dy) {
        int yy = cy + dy; if (yy < 0 || yy >= NB) continue;
        for (int dx = -1; dx <= 1; ++dx) {
            int xx = cx + dx; if (xx < 0 || xx >= NB) continue;
            int nc = yy * NB + xx;
            int off = gtOff[c * NC + nc], cnt = gtCnt[c * NC + nc];
            for (int i = tid; i < cnt; i += MBS) {
                sB[total + i] = gtBox[c * G + off + i];
                sE[total + i] = gtAbe[c * G + off + i];
                sG[total + i] = gtIdx[c * G + off + i];
            }
            total += cnt;   // uniform across threads
        }
    }
    __syncthreads();

    const size_t cp = (size_t)c * P;
    for (int i = tid; i < pCnt; i += MBS) {
        float4 pb = sBox[cp + pOff + i];           // coalesced float4
        float ax1 = pb.x, ay1 = pb.y, ax2 = pb.z, ay2 = pb.w;
        float A   = __fmul_rn(__fsub_rn(ax2, ax1), __fsub_rn(ay2, ay1));
        float IN = 0.0f, SB = 1.0f;
        int mj = -1;
        #pragma unroll 4
        for (int j = 0; j < total; ++j) {
            float4 b = sB[j];
            float lx = fmaxf(ax1, b.x), ly = fmaxf(ay1, b.y);
            float rx = fminf(ax2, b.z), ry = fminf(ay2, b.w);
            float wx = fmaxf(__fsub_rn(rx, lx), 0.0f);
            float wy = fmaxf(__fsub_rn(ry, ly), 0.0f);
            float in = __fmul_rn(wx, wy);
            float sb = __fadd_rn(A, sE[j]);
            bool  up = __fmul_rn(in, SB) > __fmul_rn(IN, sb);
            IN = up ? in : IN; SB = up ? sb : SB; mj = up ? j : mj;
        }
        if (IN > 0.0f) {   // zero-inter preds can never be valid
            float4 b = sB[mj];
            float area = __fmul_rn(__fsub_rn(b.z, b.x), __fsub_rn(b.w, b.y));
            float dn = __fadd_rn(__fsub_rn(__fadd_rn(A, area), IN), 1e-9f);
            if (__fdiv_rn(IN, dn) > 0.5f) {        // exact reference iou
                int p = (int)sPid[cp + pOff + i];
                atomicMax(&gtKey[c * G + sG[mj]], pack_key(scoreC[cp + p], p));
            }
        }
    }
}

// ---------------- L4: sortc — compact gtKey + position-sort, 1 blk/class ----
// O(T^2) LDS broadcast position-sort (keys unique, T <= 800) into a
// 1024-padded descending array (pad = 0 sorts last; real keys > 0).
__global__ __launch_bounds__(BS) void sortc_kernel(
        const unsigned long long* __restrict__ gtKey,
        unsigned long long* __restrict__ sortedKeys, int* __restrict__ sortT) {
    __shared__ unsigned long long k[G];
    __shared__ unsigned long long sk[1024];
    __shared__ int cnt;
    const int c = blockIdx.x, tid = threadIdx.x;
    if (tid == 0) cnt = 0;
    for (int j = tid; j < 1024; j += BS) sk[j] = 0ull;
    __syncthreads();
    for (int i = tid; i < G; i += BS) {
        unsigned long long key = gtKey[c * G + i];
        if (key != 0ull) k[atomicAdd(&cnt, 1)] = key;
    }
    __syncthreads();
    const int T = cnt;
    if (tid == 0) sortT[c] = T;
    for (int t = tid; t < T; t += BS) {
        unsigned long long key = k[t];
        int pos = 0;
        for (int u = 0; u < T; ++u) pos += (k[u] > key) ? 1 : 0;   // keys unique
        sk[pos] = key;
    }
    __syncthreads();
    for (int j = tid; j < 1024; j += BS) sortedKeys[c * 1024 + j] = sk[j];
}

// ---------------- L5: hist — pos(q) for every pred via binary search --------
// pos(q) = #{TP keys > key_q}. rank(s) = prefix(hist)[s] - 1 (self removed).
// 640 blocks keep the chip busy (R8's 80-block fusion was the tail stall).
__global__ __launch_bounds__(BS) void hist_kernel(
        const float* __restrict__ scoreC,
        const unsigned long long* __restrict__ sortedKeys,
        int* __restrict__ gHist) {
    __shared__ unsigned long long sK[1024];
    __shared__ int h[1024];
    const int c = blockIdx.y, tid = threadIdx.x;
    for (int j = tid; j < 1024; j += BS) { sK[j] = sortedKeys[c * 1024 + j]; h[j] = 0; }
    __syncthreads();
    const int start = blockIdx.x * CHSZ;
    const int end   = min(start + CHSZ, P);
    const float* sc = scoreC + (size_t)c * P;
    for (int i = start + tid; i < end; i += BS) {
        unsigned long long kq =
            ((unsigned long long)__float_as_uint(sc[i]) << 32) | (unsigned)(P - 1 - i);
        int lo = 0;   // count of sorted-desc keys > kq (pads are 0, never > kq)
        #pragma unroll
        for (int step = 512; step > 0; step >>= 1)
            if (sK[lo + step - 1] > kq) lo += step;
        atomicAdd(&h[lo], 1);   // LDS
    }
    __syncthreads();
    for (int j = tid; j < 1024; j += BS)
        if (h[j]) atomicAdd(&gHist[c * 1024 + j], h[j]);   // no-return
}

// ---------------- L6: ap — prefix over hist + closed-form terms + mean ------
// TP at sorted position s has ordinal k = s+1 and sorted rank r = prefix-1.
// precision = k/(r+1) exactly (ctp+cfp == r+1; 1e-9 rounds away in f32);
// term = ((k/800 - (k-1)/800) * (k/(r+1) + (k-1)/r)) * 0.5 — reference op
// order; r == 0 contributes nothing. Last-arriving class block computes the
// mean with a deterministic serial in-order sum.
__global__ __launch_bounds__(BS) void ap2_kernel(
        const int* __restrict__ sortT, const int* __restrict__ gHist,
        float* __restrict__ ap, int* __restrict__ doneCnt,
        float* __restrict__ out) {
    __shared__ int ha[1024];
    __shared__ int hb[1024];
    __shared__ float red[BS];
    __shared__ int lastFlag;
    __shared__ float sap[C];
    const int c = blockIdx.x, tid = threadIdx.x;
    const int T = sortT[c];
    for (int j = tid; j < 1024; j += BS) ha[j] = gHist[c * 1024 + j];
    __syncthreads();
    int* src = ha; int* dst = hb;
    for (int o = 1; o < 1024; o <<= 1) {
        for (int j = tid; j < 1024; j += BS)
            dst[j] = src[j] + ((j >= o) ? src[j - o] : 0);
        __syncthreads();
        int* tmp = src; src = dst; dst = tmp;
    }
    float sum = 0.0f;
    for (int s = tid; s < T; s += BS) {
        int r = src[s] - 1;          // inclusive prefix minus self
        if (r >= 1) {
            float kf  = (float)(s + 1);
            float km  = (float)s;
            float ri  = __fdiv_rn(kf, 800.0f);
            float rim = __fdiv_rn(km, 800.0f);
            float pi  = __fdiv_rn(kf, (float)(r + 1));
            float pim = __fdiv_rn(km, (float)r);
            sum = __fadd_rn(sum,
                  __fmul_rn(__fmul_rn(__fsub_rn(ri, rim), __fadd_rn(pi, pim)), 0.5f));
        }
    }
    red[tid] = sum;
    __syncthreads();
    for (int s2 = BS / 2; s2 > 0; s2 >>= 1) {
        if (tid < s2) red[tid] = __fadd_rn(red[tid], red[tid + s2]);
        __syncthreads();
    }
    if (tid == 0) {
        ap[c] = red[0];
        __threadfence();                                  // publish ap[c]
        lastFlag = (atomicAdd(doneCnt, 1) == C - 1);      // device-scope
    }
    __syncthreads();
    if (lastFlag) {
        __threadfence();                                  // acquire all ap[]
        if (tid < C) sap[tid] = ((volatile float*)ap)[tid];
        __syncthreads();
        if (tid == 0) {
            float s = 0.0f;
            for (int cc = 0; cc < C; ++cc) s = __fadd_rn(s, sap[cc]);
            out[0] = __fdiv_rn(s, 80.0f);
        }
    }
}

extern "C" void kernel_launch(void* const* d_in, const int* in_sizes, int n_in,
                              void* d_out, int out_size, void* d_ws, size_t ws_size,
                              hipStream_t stream) {
    const float* pred = (const float*)d_in[0];   // [C, P, 7] f32
    const float* gt   = (const float*)d_in[1];   // [C, G, 7] f32
    float* out = (float*)d_out;

    // Workspace layout (~55.9 MB; R7 confirmed ws_size >= 55935488 by taking
    // the staged path). [0, 368704) is memset-zeroed (doneCnt, predCnt,
    // predCur0, gHist); gtKey is zeroed by prep's gt blocks.
    char* ws = (char*)d_ws;
    int*                doneCnt    = (int*)               (ws + 0);         // 64 B
    int*                predCnt    = (int*)               (ws + 64);        // 20480 B
    int*                predCur0   = (int*)               (ws + 20544);     // 20480 B
    int*                gHist      = (int*)               (ws + 41024);     // 327680 B
    float*              ap         = (float*)             (ws + 368704);    // 320 B
    int*                sortT      = (int*)               (ws + 369024);    // 320 B
    int*                gtCnt      = (int*)               (ws + 369664);    // 20480 B
    int*                gtOff      = (int*)               (ws + 390144);    // 20480 B
    int*                gtIdx      = (int*)               (ws + 410624);    // 256000 B
    float*              gtAbe      = (float*)             (ws + 666624);    // 256000 B
    unsigned long long* gtKey      = (unsigned long long*)(ws + 922624);    // 512000 B
    unsigned long long* sortedKeys = (unsigned long long*)(ws + 1434624);   // 655360 B
    float4*             gtBox      = (float4*)            (ws + 2090240);   // 1.024 MB (16-aligned)
    float*              scoreC     = (float*)             (ws + 3114240);   // 9.6 MB
    float4*             sBox       = (float4*)            (ws + 12714240);  // 38.4 MB (16-aligned)
    unsigned short*     sPid       = (unsigned short*)    (ws + 51114240);  // 4.8 MB
    // end: 55914240 B

    hipMemsetAsync(ws, 0, 368704, stream);   // doneCnt + predCnt + predCur0 + gHist
    prep_kernel<<<dim3(P_BLK + 1, C), BS, 0, stream>>>(
        pred, gt, predCnt, scoreC, gtCnt, gtOff, gtBox, gtAbe, gtIdx, gtKey);
    scatter_kernel<<<dim3(P_BLK, C), BS, 0, stream>>>(
        pred, predCnt, predCur0, sBox, sPid);
    match_kernel<<<dim3(NC, C), MBS, 0, stream>>>(
        predCnt, gtOff, gtCnt, gtBox, gtAbe, gtIdx, sBox, sPid, scoreC, gtKey);
    sortc_kernel<<<C, BS, 0, stream>>>(gtKey, sortedKeys, sortT);
    hist_kernel<<<dim3(HCH, C), BS, 0, stream>>>(scoreC, sortedKeys, gHist);
    ap2_kernel<<<C, BS, 0, stream>>>(sortT, gHist, ap, doneCnt, out);
}